// Round 14
// baseline (70.711 us; speedup 1.0000x reference)
//
#include <hip/hip_runtime.h>

// Point-splat renderer, round 14: binsort v2 (dense regions, 1024 blocks,
// vectorized loads) + tile-max paint.
//
//  R13 post-mortem: binsort was 42 us, latency-bound (Occ 28%, VALU 15%,
//  1.6 TB/s). Fixes:
//   - NB=1024 x TB=512: 4 blocks/CU, 32 waves/CU; LDS 30 KB.
//   - DENSE regions (region = ppb, no per-tile align8): the 8-padding was
//     only needed in R11's tile-major layout; block-major regions are
//     exclusively owned, and R13's histG column writes prove sub-sector
//     interleaved plain stores merge correctly (L2 byte-mask writeback).
//     Write footprint 30 MB -> 16 MB, perfect sector efficiency.
//   - float4x3 loads: 4 points / 48 B per iteration per lane.
//
//  Kernel 1 (binsort): project 4 pts/iter -> stash packed pix in LDS +
//  LDS histogram; exclusive scan of raw counts; publish (base<<16|count)
//  to histG[t*NB+b]; replay stash through LDS cursors -> dense stores of
//  (lp<<22|idx) into the block's private bins region.
//  Kernel 2 (paint): block per tile; thread walks runs b=tid, tid+512
//  (exact counts, nothing else read); LDS atomicMax(idx+1); gather colors,
//  write CHW planes.  Max is order-free -> deterministic.
//
// Inputs: d_in[0] positions (N*3 f32), d_in[1] colors (N*3 f32),
//         d_in[2] camera_pose (16 f32), d_in[3] intrinsics (9 f32),
//         d_in[4] H (1 int), d_in[5] W (1 int)
// Output: (1,3,H,W) f32 flat.

#define NB      1024           // binsort blocks
#define TB      512            // threads per block (binsort & paint)
#define NT      1024           // 32x32 grid of 32x32-px tiles
#define PPB_MAX 4096           // stash capacity (LDS words)
#define IMGW    1024
#define IMGHW   (1024 * 1024)

__host__ __device__ __forceinline__ unsigned align8u(unsigned x) {
    return (x + 7u) & ~7u;
}

__global__ void __launch_bounds__(TB)
binsort_kernel(const float* __restrict__ pos,
               const float* __restrict__ pose,
               const float* __restrict__ intr,
               unsigned* __restrict__ bins,
               unsigned* __restrict__ histG,
               int n, int ppb, int region) {
    __shared__ unsigned stash[PPB_MAX];
    __shared__ unsigned h[NT];
    __shared__ unsigned base_[NT];
    __shared__ unsigned cur[NT];
    __shared__ unsigned sc[TB];

    int tid = threadIdx.x;
    for (int t = tid; t < NT; t += TB) h[t] = 0;
    __syncthreads();

    float r00 = pose[0], r01 = pose[1], r02 = pose[2],  t0 = pose[3];
    float r10 = pose[4], r11 = pose[5], r12 = pose[6],  t1 = pose[7];
    float r20 = pose[8], r21 = pose[9], r22 = pose[10], t2 = pose[11];
    float fx = intr[0], cx = intr[2];
    float fy = intr[4], cy = intr[5];

    int start = blockIdx.x * ppb;            // ppb is a multiple of 4
    int cnt = min(start + ppb, n) - start;
    if (cnt < 0) cnt = 0;

    // ---- pass 1: project 4 points/iter (float4 x3), stash + histogram ----
    const float4* p4 = (const float4*)(pos + (size_t)3 * (size_t)start);
    for (int j4 = tid * 4; j4 < cnt; j4 += TB * 4) {
        int g = j4 >> 2;
        float4 A = p4[3 * g + 0];
        float4 B = p4[3 * g + 1];
        float4 C = p4[3 * g + 2];
        float xs0 = A.x, ys0 = A.y, zs0 = A.z;
        float xs1 = A.w, ys1 = B.x, zs1 = B.y;
        float xs2 = B.z, ys2 = B.w, zs2 = C.x;
        float xs3 = C.y, ys3 = C.z, zs3 = C.w;

        unsigned pv[4];
        #define PROJ(K, PX, PY, PZ)                                          \
        {                                                                    \
            float x = r00 * PX + r01 * PY + r02 * PZ + t0;                   \
            float y = r10 * PX + r11 * PY + r12 * PZ + t1;                   \
            float z = r20 * PX + r21 * PY + r22 * PZ + t2;                   \
            float u = fx * x / z + cx;                                       \
            float v = fy * y / z + cy;                                       \
            int xi = (int)u;                                                 \
            int yi = (int)v;                                                 \
            unsigned p = 0xFFFFFFFFu;                                        \
            if ((j4 + K) < cnt && xi >= 0 && xi < IMGW && yi >= 0 &&         \
                yi < IMGW) {                                                 \
                p = ((unsigned)yi << 10) | (unsigned)xi;                     \
                int tt = ((yi >> 5) << 5) + (xi >> 5);                       \
                atomicAdd(&h[tt], 1u);                                       \
            }                                                                \
            pv[K] = p;                                                       \
        }
        PROJ(0, xs0, ys0, zs0)
        PROJ(1, xs1, ys1, zs1)
        PROJ(2, xs2, ys2, zs2)
        PROJ(3, xs3, ys3, zs3)
        #undef PROJ

        if (j4 + 3 < cnt) {
            *(uint4*)&stash[j4] = make_uint4(pv[0], pv[1], pv[2], pv[3]);
        } else {
            for (int k = 0; k < 4 && j4 + k < cnt; ++k) stash[j4 + k] = pv[k];
        }
    }
    __syncthreads();

    // ---- exclusive scan of raw counts (thread owns tiles 2t, 2t+1) ----
    unsigned c0 = h[2 * tid];
    unsigned c1 = h[2 * tid + 1];
    unsigned v = c0 + c1;
    sc[tid] = v;
    __syncthreads();
    for (int off = 1; off < TB; off <<= 1) {
        unsigned add = (tid >= off) ? sc[tid - off] : 0u;
        __syncthreads();
        v += add;
        sc[tid] = v;
        __syncthreads();
    }
    base_[2 * tid]     = v - c0 - c1;
    base_[2 * tid + 1] = v - c1;
    __syncthreads();

    // ---- publish (base<<16 | count); init cursors ----
    for (int t = tid; t < NT; t += TB) {
        cur[t] = base_[t];
        histG[(size_t)t * NB + blockIdx.x] = (base_[t] << 16) | h[t];
    }
    __syncthreads();

    // ---- pass 2: replay stash -> dense stores into private region ----
    unsigned* myRegion = bins + (size_t)blockIdx.x * (size_t)region;
    for (int j = tid; j < cnt; j += TB) {
        unsigned pv = stash[j];
        if (pv == 0xFFFFFFFFu) continue;
        unsigned xi = pv & 1023u, yi = pv >> 10;
        unsigned t  = ((yi >> 5) << 5) + (xi >> 5);
        unsigned lp = ((yi & 31u) << 5) + (xi & 31u);
        unsigned slot = atomicAdd(&cur[t], 1u);         // LDS
        myRegion[slot] = (lp << 22) | (unsigned)(start + j);
    }
}

__global__ void __launch_bounds__(TB)
paint_kernel(const unsigned* __restrict__ bins,
             const unsigned* __restrict__ histG,
             const float* __restrict__ colors,
             float* __restrict__ out,
             int region) {
    __shared__ unsigned win[NT];    // winner index + 1 per local pixel
    int t = blockIdx.x;
    int tid = threadIdx.x;
    for (int l = tid; l < NT; l += TB) win[l] = 0;
    __syncthreads();

    // thread walks runs b = tid, tid+TB, ... (exact counts, pads unread)
    for (int b = tid; b < NB; b += TB) {
        unsigned pk = histG[(size_t)t * NB + b];
        unsigned sbase = pk >> 16, cnt = pk & 0xFFFFu;
        const unsigned* seg = bins + (size_t)b * (size_t)region + sbase;
        for (unsigned k = 0; k < cnt; ++k) {
            unsigned e = seg[k];
            atomicMax(&win[e >> 22], (e & 0x3FFFFFu) + 1u); // LDS
        }
    }
    __syncthreads();

    int tx = (t & 31) << 5, ty = (t >> 5) << 5;
    for (int l = tid; l < NT; l += TB) {
        unsigned w = win[l];
        float r = 0.0f, g = 0.0f, bl = 0.0f;
        if (w) {
            unsigned wi = w - 1u;
            r  = fminf(fmaxf(colors[3 * wi + 0], 0.0f), 1.0f);
            g  = fminf(fmaxf(colors[3 * wi + 1], 0.0f), 1.0f);
            bl = fminf(fmaxf(colors[3 * wi + 2], 0.0f), 1.0f);
        }
        int x = tx + (l & 31), y = ty + (l >> 5);
        int p = y * IMGW + x;
        out[p] = r;
        out[IMGHW + p] = g;
        out[2 * IMGHW + p] = bl;
    }
}

// ---------- fallback: memset + single atomic pass + paint ----------

__global__ void proj_simple(const float* __restrict__ pos,
                            const float* __restrict__ pose,
                            const float* __restrict__ intr,
                            const int* __restrict__ Hp,
                            const int* __restrict__ Wp,
                            int* __restrict__ winner, int n) {
    int i = blockIdx.x * blockDim.x + threadIdx.x;
    if (i >= n) return;
    float px = pos[3 * i], py = pos[3 * i + 1], pz = pos[3 * i + 2];
    float x = pose[0] * px + pose[1] * py + pose[2]  * pz + pose[3];
    float y = pose[4] * px + pose[5] * py + pose[6]  * pz + pose[7];
    float z = pose[8] * px + pose[9] * py + pose[10] * pz + pose[11];
    float u = intr[0] * x / z + intr[2];
    float v = intr[4] * y / z + intr[5];
    int xi = (int)u, yi = (int)v;
    int W = *Wp, H = *Hp;
    if (xi >= 0 && xi < W && yi >= 0 && yi < H) atomicMax(&winner[yi * W + xi], i);
}

__global__ void paint_simple(const int* __restrict__ winner,
                             const float* __restrict__ colors,
                             float* __restrict__ out, int HW) {
    int p = blockIdx.x * blockDim.x + threadIdx.x;
    if (p >= HW) return;
    int w = winner[p];
    float r = 0.0f, g = 0.0f, b = 0.0f;
    if (w >= 0) {
        r = fminf(fmaxf(colors[3 * w + 0], 0.0f), 1.0f);
        g = fminf(fmaxf(colors[3 * w + 1], 0.0f), 1.0f);
        b = fminf(fmaxf(colors[3 * w + 2], 0.0f), 1.0f);
    }
    out[p] = r; out[HW + p] = g; out[2 * HW + p] = b;
}

extern "C" void kernel_launch(void* const* d_in, const int* in_sizes, int n_in,
                              void* d_out, int out_size, void* d_ws, size_t ws_size,
                              hipStream_t stream) {
    const float* positions = (const float*)d_in[0];
    const float* colors    = (const float*)d_in[1];
    const float* pose      = (const float*)d_in[2];
    const float* intr      = (const float*)d_in[3];
    const int*   Hp        = (const int*)d_in[4];
    const int*   Wp        = (const int*)d_in[5];
    float* out = (float*)d_out;

    int n  = in_sizes[0] / 3;       // number of points
    int HW = out_size / 3;          // H*W pixels

    int ppb = ((n + NB - 1) / NB + 3) & ~3;             // multiple of 4
    int region = (int)align8u((unsigned)ppb);           // dense, 32B-aligned
    unsigned* bins  = (unsigned*)d_ws;
    unsigned* histG = bins + (size_t)NB * (size_t)region;
    size_t needFast = ((size_t)NB * region + (size_t)NT * NB) * sizeof(unsigned);

    bool fast = (HW == IMGHW) && (n >= 4096) && (ppb <= PPB_MAX) &&
                (n <= 4000000) && (ws_size >= needFast);

    if (fast) {
        binsort_kernel<<<NB, TB, 0, stream>>>(positions, pose, intr,
                                              bins, histG, n, ppb, region);
        paint_kernel<<<NT, TB, 0, stream>>>(bins, histG, colors, out, region);
        return;
    }

    // ---- fallback ----
    int* winner = (int*)d_ws;
    const int block = 256;
    hipMemsetAsync(winner, 0xFF, (size_t)HW * sizeof(int), stream);
    int grid = (n + block - 1) / block;
    proj_simple<<<grid, block, 0, stream>>>(positions, pose, intr, Hp, Wp,
                                            winner, n);
    int grid2 = (HW + block - 1) / block;
    paint_simple<<<grid2, block, 0, stream>>>(winner, colors, out, HW);
}

// Round 15
// 63.420 us; speedup vs baseline: 1.1150x; 1.1150x over previous
//
#include <hip/hip_runtime.h>

// Point-splat renderer, round 15: recombine R13's paint-friendly layout
// (NB=512, align8-padded 32B-aligned runs) with R14's binsort speedups
// (full wave occupancy, float4x3 loads).
//
//  R14 post-mortem: paint FETCH 85.7 MB (1M tiny unaligned runs x 64B line
//  each); binsort improved to ~25us. R13 paint was ~16us with 512 aligned
//  runs/tile. This round:
//   - binsort: NB=512 blocks x TB=1024 thr = 2 blocks/CU x 16 waves = 32
//     waves/CU (100%); LDS 47KB; float4x3 loads, 4 points/lane/iter.
//   - align8 per-(block,tile) sub-segments: every run starts 32B-aligned,
//     avg ~8 entries -> ~1 line per run; paint fetch ~20MB for bins.
//   - paint: NT=1024 tile-blocks x 512 thr (4 blocks/CU), exactly one run
//     per thread, exact counts (pads never read), LDS atomicMax, gather,
//     CHW stores.
//  winner = max index is order-free -> deterministic.
//
// Inputs: d_in[0] positions (N*3 f32), d_in[1] colors (N*3 f32),
//         d_in[2] camera_pose (16 f32), d_in[3] intrinsics (9 f32),
//         d_in[4] H (1 int), d_in[5] W (1 int)
// Output: (1,3,H,W) f32 flat.

#define NB      512            // binsort blocks
#define TBS     1024           // binsort threads per block
#define TBP     512            // paint threads per block
#define NT      1024           // 32x32 grid of 32x32-px tiles
#define PPB_MAX 7936           // stash capacity (LDS words)
#define IMGW    1024
#define IMGHW   (1024 * 1024)

__host__ __device__ __forceinline__ unsigned align8u(unsigned x) {
    return (x + 7u) & ~7u;
}

__global__ void __launch_bounds__(TBS)
binsort_kernel(const float* __restrict__ pos,
               const float* __restrict__ pose,
               const float* __restrict__ intr,
               unsigned* __restrict__ bins,
               unsigned* __restrict__ histG,
               int n, int ppb, int region) {
    __shared__ unsigned stash[PPB_MAX];
    __shared__ unsigned h[NT];
    __shared__ unsigned base_[NT];
    __shared__ unsigned cur[NT];
    __shared__ unsigned sc[TBS];

    int tid = threadIdx.x;
    h[tid] = 0;                        // TBS == NT
    __syncthreads();

    float r00 = pose[0], r01 = pose[1], r02 = pose[2],  t0 = pose[3];
    float r10 = pose[4], r11 = pose[5], r12 = pose[6],  t1 = pose[7];
    float r20 = pose[8], r21 = pose[9], r22 = pose[10], t2 = pose[11];
    float fx = intr[0], cx = intr[2];
    float fy = intr[4], cy = intr[5];

    int start = blockIdx.x * ppb;      // ppb is a multiple of 4
    int cnt = min(start + ppb, n) - start;
    if (cnt < 0) cnt = 0;

    // ---- pass 1: project 4 points/iter (float4 x3), stash + histogram ----
    const float4* p4 = (const float4*)(pos + (size_t)3 * (size_t)start);
    for (int j4 = tid * 4; j4 < cnt; j4 += TBS * 4) {
        int g = j4 >> 2;
        float4 A = p4[3 * g + 0];
        float4 B = p4[3 * g + 1];
        float4 C = p4[3 * g + 2];
        float xs0 = A.x, ys0 = A.y, zs0 = A.z;
        float xs1 = A.w, ys1 = B.x, zs1 = B.y;
        float xs2 = B.z, ys2 = B.w, zs2 = C.x;
        float xs3 = C.y, ys3 = C.z, zs3 = C.w;

        unsigned pv[4];
        #define PROJ(K, PX, PY, PZ)                                          \
        {                                                                    \
            float x = r00 * PX + r01 * PY + r02 * PZ + t0;                   \
            float y = r10 * PX + r11 * PY + r12 * PZ + t1;                   \
            float z = r20 * PX + r21 * PY + r22 * PZ + t2;                   \
            float u = fx * x / z + cx;                                       \
            float v = fy * y / z + cy;                                       \
            int xi = (int)u;                                                 \
            int yi = (int)v;                                                 \
            unsigned p = 0xFFFFFFFFu;                                        \
            if ((j4 + K) < cnt && xi >= 0 && xi < IMGW && yi >= 0 &&         \
                yi < IMGW) {                                                 \
                p = ((unsigned)yi << 10) | (unsigned)xi;                     \
                int tt = ((yi >> 5) << 5) + (xi >> 5);                       \
                atomicAdd(&h[tt], 1u);                                       \
            }                                                                \
            pv[K] = p;                                                       \
        }
        PROJ(0, xs0, ys0, zs0)
        PROJ(1, xs1, ys1, zs1)
        PROJ(2, xs2, ys2, zs2)
        PROJ(3, xs3, ys3, zs3)
        #undef PROJ

        if (j4 + 3 < cnt) {
            *(uint4*)&stash[j4] = make_uint4(pv[0], pv[1], pv[2], pv[3]);
        } else {
            for (int k = 0; k < 4 && j4 + k < cnt; ++k) stash[j4 + k] = pv[k];
        }
    }
    __syncthreads();

    // ---- exclusive scan of 8-PADDED counts (thread owns tile tid) ----
    unsigned a0 = align8u(h[tid]);
    unsigned v = a0;
    sc[tid] = v;
    __syncthreads();
    for (int off = 1; off < TBS; off <<= 1) {
        unsigned add = (tid >= off) ? sc[tid - off] : 0u;
        __syncthreads();
        v += add;
        sc[tid] = v;
        __syncthreads();
    }
    base_[tid] = v - a0;               // 8-aligned -> 32B-aligned runs
    __syncthreads();

    // ---- publish (base<<16 | count); init cursors ----
    cur[tid] = base_[tid];
    histG[(size_t)tid * NB + blockIdx.x] = (base_[tid] << 16) | h[tid];
    __syncthreads();

    // ---- pass 2: replay stash -> stores into private region ----
    unsigned* myRegion = bins + (size_t)blockIdx.x * (size_t)region;
    for (int j = tid; j < cnt; j += TBS) {
        unsigned pv = stash[j];
        if (pv == 0xFFFFFFFFu) continue;
        unsigned xi = pv & 1023u, yi = pv >> 10;
        unsigned t  = ((yi >> 5) << 5) + (xi >> 5);
        unsigned lp = ((yi & 31u) << 5) + (xi & 31u);
        unsigned slot = atomicAdd(&cur[t], 1u);         // LDS
        myRegion[slot] = (lp << 22) | (unsigned)(start + j);
    }
}

__global__ void __launch_bounds__(TBP)
paint_kernel(const unsigned* __restrict__ bins,
             const unsigned* __restrict__ histG,
             const float* __restrict__ colors,
             float* __restrict__ out,
             int region) {
    __shared__ unsigned win[NT];    // winner index + 1 per local pixel
    int t = blockIdx.x;
    int tid = threadIdx.x;
    win[tid] = 0;
    win[tid + TBP] = 0;
    __syncthreads();

    // thread tid owns run (block tid, tile t): 32B-aligned, exact count
    {
        unsigned pk = histG[(size_t)t * NB + tid];
        unsigned sbase = pk >> 16, cnt = pk & 0xFFFFu;
        const unsigned* seg = bins + (size_t)tid * (size_t)region + sbase;
        for (unsigned k = 0; k < cnt; ++k) {
            unsigned e = seg[k];
            atomicMax(&win[e >> 22], (e & 0x3FFFFFu) + 1u); // LDS
        }
    }
    __syncthreads();

    int tx = (t & 31) << 5, ty = (t >> 5) << 5;
    for (int l = tid; l < NT; l += TBP) {
        unsigned w = win[l];
        float r = 0.0f, g = 0.0f, bl = 0.0f;
        if (w) {
            unsigned wi = w - 1u;
            r  = fminf(fmaxf(colors[3 * wi + 0], 0.0f), 1.0f);
            g  = fminf(fmaxf(colors[3 * wi + 1], 0.0f), 1.0f);
            bl = fminf(fmaxf(colors[3 * wi + 2], 0.0f), 1.0f);
        }
        int x = tx + (l & 31), y = ty + (l >> 5);
        int p = y * IMGW + x;
        out[p] = r;
        out[IMGHW + p] = g;
        out[2 * IMGHW + p] = bl;
    }
}

// ---------- fallback: memset + single atomic pass + paint ----------

__global__ void proj_simple(const float* __restrict__ pos,
                            const float* __restrict__ pose,
                            const float* __restrict__ intr,
                            const int* __restrict__ Hp,
                            const int* __restrict__ Wp,
                            int* __restrict__ winner, int n) {
    int i = blockIdx.x * blockDim.x + threadIdx.x;
    if (i >= n) return;
    float px = pos[3 * i], py = pos[3 * i + 1], pz = pos[3 * i + 2];
    float x = pose[0] * px + pose[1] * py + pose[2]  * pz + pose[3];
    float y = pose[4] * px + pose[5] * py + pose[6]  * pz + pose[7];
    float z = pose[8] * px + pose[9] * py + pose[10] * pz + pose[11];
    float u = intr[0] * x / z + intr[2];
    float v = intr[4] * y / z + intr[5];
    int xi = (int)u, yi = (int)v;
    int W = *Wp, H = *Hp;
    if (xi >= 0 && xi < W && yi >= 0 && yi < H) atomicMax(&winner[yi * W + xi], i);
}

__global__ void paint_simple(const int* __restrict__ winner,
                             const float* __restrict__ colors,
                             float* __restrict__ out, int HW) {
    int p = blockIdx.x * blockDim.x + threadIdx.x;
    if (p >= HW) return;
    int w = winner[p];
    float r = 0.0f, g = 0.0f, b = 0.0f;
    if (w >= 0) {
        r = fminf(fmaxf(colors[3 * w + 0], 0.0f), 1.0f);
        g = fminf(fmaxf(colors[3 * w + 1], 0.0f), 1.0f);
        b = fminf(fmaxf(colors[3 * w + 2], 0.0f), 1.0f);
    }
    out[p] = r; out[HW + p] = g; out[2 * HW + p] = b;
}

extern "C" void kernel_launch(void* const* d_in, const int* in_sizes, int n_in,
                              void* d_out, int out_size, void* d_ws, size_t ws_size,
                              hipStream_t stream) {
    const float* positions = (const float*)d_in[0];
    const float* colors    = (const float*)d_in[1];
    const float* pose      = (const float*)d_in[2];
    const float* intr      = (const float*)d_in[3];
    const int*   Hp        = (const int*)d_in[4];
    const int*   Wp        = (const int*)d_in[5];
    float* out = (float*)d_out;

    int n  = in_sizes[0] / 3;       // number of points
    int HW = out_size / 3;          // H*W pixels

    int ppb = ((n + NB - 1) / NB + 3) & ~3;             // multiple of 4
    int region = (int)align8u((unsigned)ppb) + 7 * NT;  // padded worst case
    unsigned* bins  = (unsigned*)d_ws;
    unsigned* histG = bins + (size_t)NB * (size_t)region;
    size_t needFast = ((size_t)NB * region + (size_t)NT * NB) * sizeof(unsigned);

    bool fast = (HW == IMGHW) && (n >= 4096) && ((n & 3) == 0) &&
                (ppb <= PPB_MAX) && (n <= 4000000) && (ws_size >= needFast);

    if (fast) {
        binsort_kernel<<<NB, TBS, 0, stream>>>(positions, pose, intr,
                                               bins, histG, n, ppb, region);
        paint_kernel<<<NT, TBP, 0, stream>>>(bins, histG, colors, out, region);
        return;
    }

    // ---- fallback ----
    int* winner = (int*)d_ws;
    const int block = 256;
    hipMemsetAsync(winner, 0xFF, (size_t)HW * sizeof(int), stream);
    int grid = (n + block - 1) / block;
    proj_simple<<<grid, block, 0, stream>>>(positions, pose, intr, Hp, Wp,
                                            winner, n);
    int grid2 = (HW + block - 1) / block;
    paint_simple<<<grid2, block, 0, stream>>>(winner, colors, out, HW);
}